// Round 3
// baseline (1122.133 us; speedup 1.0000x reference)
//
#include <hip/hip_runtime.h>

#define DI __device__ __forceinline__

typedef unsigned int uint;
typedef unsigned short ushort;
typedef _Float16 half2t __attribute__((ext_vector_type(2)));

#define VOCAB 50257
#define NEMB 48
#define HID 128
#define G4 512
#define NCLS 2000
#define BATCH 512
#define SEQ 1024

#if __has_builtin(__builtin_amdgcn_fdot2)
DI float fdot2(half2t a, half2t b, float c) { return __builtin_amdgcn_fdot2(a, b, c, false); }
#else
DI float fdot2(half2t a, half2t b, float c) { return c + (float)a.x * (float)b.x + (float)a.y * (float)b.y; }
#endif

DI float sigm(float x) {
  return __builtin_amdgcn_rcpf(1.0f + __builtin_amdgcn_exp2f(-1.4426950408889634f * x));
}
DI float tanhfast(float x) {
  return 1.0f - 2.0f * __builtin_amdgcn_rcpf(__builtin_amdgcn_exp2f(2.8853900817779268f * x) + 1.0f);
}

// Barrier that drains ONLY LDS (lgkmcnt), leaving global-load prefetches
// (vmcnt) in flight across the barrier.
DI void barrier_lds_only() {
  asm volatile("s_waitcnt lgkmcnt(0)" ::: "memory");
  __builtin_amdgcn_s_barrier();
  asm volatile("" ::: "memory");
}

// ---------------------------------------------------------------------------
// Phase A: P[v][j] = emb[v] . w_ih[j] + b_ih[j] + b_hh[j]  (fp32 math, f16 out)
// ---------------------------------------------------------------------------
#define VROWS 32
__global__ __launch_bounds__(512) void build_P(
    const float* __restrict__ emb, const float* __restrict__ w_ih,
    const float* __restrict__ b_ih, const float* __restrict__ b_hh,
    _Float16* __restrict__ P)
{
  __shared__ __align__(16) float eL[VROWS][NEMB];
  const int tid = threadIdx.x;
  const int v0 = blockIdx.x * VROWS;
  int nrows = VOCAB - v0; if (nrows > VROWS) nrows = VROWS;

  for (int f = tid; f < nrows * NEMB; f += 512)
    eL[f / NEMB][f % NEMB] = emb[(size_t)v0 * NEMB + f];

  float w[NEMB];
  {
    const float* wr = w_ih + (size_t)tid * NEMB;
#pragma unroll
    for (int k = 0; k < NEMB; k++) w[k] = wr[k];
  }
  float bias = b_ih[tid] + b_hh[tid];
  __syncthreads();

  for (int v = 0; v < nrows; v++) {
    const float4* e4 = (const float4*)&eL[v][0];
    float a = bias;
#pragma unroll
    for (int k = 0; k < NEMB / 4; k++) {
      float4 e = e4[k];
      a += w[4 * k] * e.x + w[4 * k + 1] * e.y + w[4 * k + 2] * e.z + w[4 * k + 3] * e.w;
    }
    P[(size_t)(v0 + v) * G4 + tid] = (_Float16)a;
  }
}

// ---------------------------------------------------------------------------
// Phase B: persistent LSTM scan, SINGLE barrier per timestep.
// 512 blocks x 512 threads (8 waves), 2 blocks/CU. Thread t: gate cols
// (t&255, t&255+256), K-half (t>>8). After the barrier, EVERY wave
// redundantly computes the gate nonlinearities for the 64 outputs of its
// own K-half (1 output/lane) and writes h into a wave-PRIVATE LDS copy
// hpriv[wave][64]. The h write->read is same-wave program order -> no
// second barrier, no 2-wave serialized gate phase. Partial sums go through
// double-buffered g2[parity] (write(t+2)/read(t) separated by barrier(t+1)).
// ---------------------------------------------------------------------------
template<bool USE_P>
__global__ __launch_bounds__(512, 4) void lstm_scan(
    const int* __restrict__ x, const float* __restrict__ emb,
    const float* __restrict__ w_ih, const float* __restrict__ w_hh,
    const float* __restrict__ b_ih, const float* __restrict__ b_hh,
    const _Float16* __restrict__ P, float* __restrict__ hout)
{
  __shared__ int tokL[SEQ];                        // 4 KB
  __shared__ __align__(16) _Float16 hpriv[8][64];  // 1 KB, wave-private h
  __shared__ float g2[2][2][G4];                   // 8 KB, [parity][kh][col]
  __shared__ __align__(8) half2t e16[2][NEMB / 2];

  const int tid = threadIdx.x;        // 0..511
  const int b = blockIdx.x;
  const int lane = tid & 63;
  const int wave = tid >> 6;          // 0..7
  const int col = tid & 255;          // owns gate cols col and col+256
  const int kh = tid >> 8;            // K-half 0/1 (wave-uniform)
  const int koff = kh * (HID / 2);
  const int oidx = koff + lane;       // output this lane gate-computes

  {
    const int* xp = x + (size_t)b * SEQ;
#pragma unroll
    for (int i = 0; i < SEQ / 512; i++) tokL[tid + 512 * i] = xp[tid + 512 * i];
  }

  // W_hh K-half rows for cols col and col+256, f16 pairs (64 VGPRs)
  half2t w0[HID / 4], w1[HID / 4];
  {
    const float4* wr0 = (const float4*)(w_hh + (size_t)col * HID + koff);
    const float4* wr1 = (const float4*)(w_hh + (size_t)(col + 256) * HID + koff);
#pragma unroll
    for (int k = 0; k < HID / 8; k++) {
      float4 a = wr0[k];
      half2t p; p.x = (_Float16)a.x; p.y = (_Float16)a.y; w0[2 * k] = p;
      p.x = (_Float16)a.z; p.y = (_Float16)a.w; w0[2 * k + 1] = p;
      float4 bv = wr1[k];
      p.x = (_Float16)bv.x; p.y = (_Float16)bv.y; w1[2 * k] = p;
      p.x = (_Float16)bv.z; p.y = (_Float16)bv.w; w1[2 * k + 1] = p;
    }
  }
  half2t wih0[NEMB / 2], wih1[NEMB / 2];
  float bias0 = 0.0f, bias1 = 0.0f;
  if (!USE_P && kh == 0) {
    const float* wr0 = w_ih + (size_t)col * NEMB;
    const float* wr1 = w_ih + (size_t)(col + 256) * NEMB;
#pragma unroll
    for (int k = 0; k < NEMB / 2; k++) {
      half2t p;
      p.x = (_Float16)wr0[2 * k]; p.y = (_Float16)wr0[2 * k + 1]; wih0[k] = p;
      p.x = (_Float16)wr1[2 * k]; p.y = (_Float16)wr1[2 * k + 1]; wih1[k] = p;
    }
    bias0 = b_ih[col] + b_hh[col];
    bias1 = b_ih[col + 256] + b_hh[col + 256];
  }
  // h(0) = 0: flat index tid maps exactly to hpriv[wave][lane] (own region)
  ((_Float16*)hpriv)[tid] = (_Float16)0.0f;
  __syncthreads(); // tokens visible

  float c = 0.0f;
  _Float16 pa0{}, pa1{}, pb0{}, pb1{};
  float2 einfl = {0.0f, 0.0f};
  if (USE_P) {
    if (kh == 0) {
      const _Float16* r0 = P + (size_t)tokL[0] * G4;
      const _Float16* r1 = P + (size_t)tokL[1] * G4;
      pa0 = r0[col]; pa1 = r0[col + 256];
      pb0 = r1[col]; pb1 = r1[col + 256];
    }
  } else {
    if (tid < NEMB / 2) {
      float2 e0 = ((const float2*)(emb + (size_t)tokL[0] * NEMB))[tid];
      einfl    = ((const float2*)(emb + (size_t)tokL[1] * NEMB))[tid];
      half2t p; p.x = (_Float16)e0.x; p.y = (_Float16)e0.y;
      e16[0][tid] = p;
    }
  }
  __syncthreads();

#define STEP(t, par) do {                                                      \
    float xg0, xg1;                                                            \
    if (USE_P) {                                                               \
      if (kh == 0) {                                                           \
        int tc = (t) + 2; if (tc > SEQ - 1) tc = SEQ - 1;                      \
        xg0 = (float)((par) ? pb0 : pa0);                                      \
        xg1 = (float)((par) ? pb1 : pa1);                                      \
        const _Float16* rn = P + (size_t)tokL[tc] * G4; /* prefetch t+2 */     \
        _Float16 n0 = rn[col], n1 = rn[col + 256];                             \
        if ((par) == 0) { pa0 = n0; pa1 = n1; } else { pb0 = n0; pb1 = n1; }   \
      } else { xg0 = 0.0f; xg1 = 0.0f; }                                       \
    } else {                                                                   \
      if (tid < NEMB / 2) {                                                    \
        int tc = (t) + 2; if (tc > SEQ - 1) tc = SEQ - 1;                      \
        half2t p; p.x = (_Float16)einfl.x; p.y = (_Float16)einfl.y;            \
        e16[((t) + 1) & 1][tid] = p;                                           \
        einfl = ((const float2*)(emb + (size_t)tokL[tc] * NEMB))[tid];         \
      }                                                                        \
      if (kh == 0) {                                                           \
        xg0 = bias0; xg1 = bias1;                                              \
        _Pragma("unroll")                                                      \
        for (int k = 0; k < NEMB / 2; k++) {                                   \
          xg0 = fdot2(wih0[k], e16[(par)][k], xg0);                            \
          xg1 = fdot2(wih1[k], e16[(par)][k], xg1);                            \
        }                                                                      \
      } else { xg0 = 0.0f; xg1 = 0.0f; }                                       \
    }                                                                          \
    /* dot phase: read own-wave h copy (broadcast reads, same-wave data) */    \
    const uint4* hv = (const uint4*)&hpriv[wave][0];                           \
    float s0 = xg0, u0 = 0.0f, s1 = xg1, u1 = 0.0f;                            \
    _Pragma("unroll")                                                          \
    for (int kt = 0; kt < HID / 16; kt++) {                                    \
      uint4 hq = hv[kt];                                                       \
      half2t ha = __builtin_bit_cast(half2t, hq.x);                            \
      half2t hb = __builtin_bit_cast(half2t, hq.y);                            \
      half2t hc = __builtin_bit_cast(half2t, hq.z);                            \
      half2t hd = __builtin_bit_cast(half2t, hq.w);                            \
      s0 = fdot2(w0[4 * kt + 0], ha, s0);                                      \
      u0 = fdot2(w0[4 * kt + 1], hb, u0);                                      \
      s0 = fdot2(w0[4 * kt + 2], hc, s0);                                      \
      u0 = fdot2(w0[4 * kt + 3], hd, u0);                                      \
      s1 = fdot2(w1[4 * kt + 0], ha, s1);                                      \
      u1 = fdot2(w1[4 * kt + 1], hb, u1);                                      \
      s1 = fdot2(w1[4 * kt + 2], hc, s1);                                      \
      u1 = fdot2(w1[4 * kt + 3], hd, u1);                                      \
    }                                                                          \
    g2[par][kh][col] = s0 + u0;                                                \
    g2[par][kh][col + 256] = s1 + u1;                                          \
    barrier_lds_only();                                                        \
    /* gate phase: ALL waves, 1 output/lane (redundant within kh-group) */     \
    {                                                                          \
      const float* gp = &g2[par][0][0];                                        \
      float gi = gp[oidx]           + gp[G4 + oidx];                           \
      float gf = gp[HID + oidx]     + gp[G4 + HID + oidx];                     \
      float gc = gp[2 * HID + oidx] + gp[G4 + 2 * HID + oidx];                 \
      float go = gp[3 * HID + oidx] + gp[G4 + 3 * HID + oidx];                 \
      float fi = sigm(gi), ff = sigm(gf), gt = tanhfast(gc), fo = sigm(go);    \
      c = ff * c + fi * gt;                                                    \
      float hh = fo * tanhfast(c);                                             \
      hpriv[wave][lane] = (_Float16)hh;                                        \
      if ((t) == SEQ - 1 && col < 64)                                          \
        hout[(size_t)b * HID + oidx] = hh;                                     \
    }                                                                          \
  } while (0)

  for (int t = 0; t < SEQ; t += 2) { STEP(t, 0); STEP(t + 1, 1); }
#undef STEP
}

// ---------------------------------------------------------------------------
// Phase C: FC  out[512,2000] = h[512,128] @ w_fc^T + b_fc.  64x64 tiles,
// K=128 staged transposed in LDS, 4x4 register blocking per thread.
// ---------------------------------------------------------------------------
#define FCR 64
#define FCC 64
__global__ __launch_bounds__(256) void fc_kernel(
    const float* __restrict__ h, const float* __restrict__ w_fc,
    const float* __restrict__ b_fc, float* __restrict__ out)
{
  __shared__ float aT[HID][FCR];
  __shared__ float bT[HID][FCC];
  const int tid = threadIdx.x;
  const int r0 = blockIdx.y * FCR;
  const int c0 = blockIdx.x * FCC;

  for (int f = tid; f < FCR * (HID / 4); f += 256) {
    int row = f >> 5, q = f & 31;
    float4 v = ((const float4*)h)[(((size_t)(r0 + row)) << 5) + q];
    aT[4 * q + 0][row] = v.x; aT[4 * q + 1][row] = v.y;
    aT[4 * q + 2][row] = v.z; aT[4 * q + 3][row] = v.w;
    int wrow = c0 + row;
    float4 wv;
    if (wrow < NCLS) wv = ((const float4*)w_fc)[(((size_t)wrow) << 5) + q];
    else { wv.x = 0.f; wv.y = 0.f; wv.z = 0.f; wv.w = 0.f; }
    bT[4 * q + 0][row] = wv.x; bT[4 * q + 1][row] = wv.y;
    bT[4 * q + 2][row] = wv.z; bT[4 * q + 3][row] = wv.w;
  }
  __syncthreads();

  const int cr = tid & 15, rr = tid >> 4;
  float acc[4][4];
#pragma unroll
  for (int i = 0; i < 4; i++)
#pragma unroll
    for (int j = 0; j < 4; j++) acc[i][j] = 0.0f;

#pragma unroll 4
  for (int k = 0; k < HID; k++) {
    float4 av = *(const float4*)&aT[k][4 * rr];
    float4 bv = *(const float4*)&bT[k][4 * cr];
    float a[4] = {av.x, av.y, av.z, av.w};
    float bb[4] = {bv.x, bv.y, bv.z, bv.w};
#pragma unroll
    for (int i = 0; i < 4; i++)
#pragma unroll
      for (int j = 0; j < 4; j++) acc[i][j] += a[i] * bb[j];
  }

#pragma unroll
  for (int j = 0; j < 4; j++) {
    int cc = c0 + 4 * cr + j;
    if (cc < NCLS) {
      float bias = b_fc[cc];
#pragma unroll
      for (int i = 0; i < 4; i++)
        out[(size_t)(r0 + 4 * rr + i) * NCLS + cc] = acc[i][j] + bias;
    }
  }
}

extern "C" void kernel_launch(void* const* d_in, const int* in_sizes, int n_in,
                              void* d_out, int out_size, void* d_ws, size_t ws_size,
                              hipStream_t stream) {
  const int*   xx   = (const int*)d_in[0];
  const float* emb  = (const float*)d_in[1];
  const float* w_ih = (const float*)d_in[2];
  const float* w_hh = (const float*)d_in[3];
  const float* b_ih = (const float*)d_in[4];
  const float* b_hh = (const float*)d_in[5];
  const float* w_fc = (const float*)d_in[6];
  const float* b_fc = (const float*)d_in[7];
  float* out = (float*)d_out;

  const size_t pbytes = (size_t)VOCAB * G4 * sizeof(_Float16); // 51.5 MB
  const size_t palign = (pbytes + 255) & ~(size_t)255;
  const size_t hbytes = (size_t)BATCH * HID * sizeof(float);

  float* hout;
  if (ws_size >= palign + hbytes) {
    _Float16* P = (_Float16*)d_ws;
    hout = (float*)((char*)d_ws + palign);
    build_P<<<(VOCAB + VROWS - 1) / VROWS, 512, 0, stream>>>(emb, w_ih, b_ih, b_hh, P);
    lstm_scan<true><<<BATCH, 512, 0, stream>>>(xx, emb, w_ih, w_hh, b_ih, b_hh, P, hout);
  } else {
    hout = (float*)d_ws;
    lstm_scan<false><<<BATCH, 512, 0, stream>>>(xx, emb, w_ih, w_hh, b_ih, b_hh,
                                                (const _Float16*)nullptr, hout);
  }
  dim3 fcg((NCLS + FCC - 1) / FCC, BATCH / FCR);
  fc_kernel<<<fcg, 256, 0, stream>>>(hout, w_fc, b_fc, out);
}

// Round 4
// 1066.825 us; speedup vs baseline: 1.0518x; 1.0518x over previous
//
#include <hip/hip_runtime.h>

#define DI __device__ __forceinline__

typedef unsigned int uint;
typedef unsigned short ushort;
typedef _Float16 half2t __attribute__((ext_vector_type(2)));
typedef _Float16 f16x8 __attribute__((ext_vector_type(8)));
typedef float f32x4 __attribute__((ext_vector_type(4)));

#define VOCAB 50257
#define NEMB 48
#define HID 128
#define G4 512
#define NCLS 2000
#define BATCH 512
#define SEQ 1024
#define MTILE 16
#define NBLK (BATCH / MTILE)   // 32 blocks

#if __has_builtin(__builtin_amdgcn_fdot2)
DI float fdot2(half2t a, half2t b, float c) { return __builtin_amdgcn_fdot2(a, b, c, false); }
#else
DI float fdot2(half2t a, half2t b, float c) { return c + (float)a.x * (float)b.x + (float)a.y * (float)b.y; }
#endif

DI float sigm(float x) {
  return __builtin_amdgcn_rcpf(1.0f + __builtin_amdgcn_exp2f(-1.4426950408889634f * x));
}
DI float tanhfast(float x) {
  return 1.0f - 2.0f * __builtin_amdgcn_rcpf(__builtin_amdgcn_exp2f(2.8853900817779268f * x) + 1.0f);
}

// Barrier draining ONLY LDS (lgkmcnt); global-load prefetches (vmcnt) stay
// in flight across it.
DI void barrier_lds_only() {
  asm volatile("s_waitcnt lgkmcnt(0)" ::: "memory");
  __builtin_amdgcn_s_barrier();
  asm volatile("" ::: "memory");
}

// ---------------------------------------------------------------------------
// Phase A: P'[v][u][g] = emb[v] . w_ih[g*128+u] + b_ih + b_hh   (f16 out)
// Gate-interleaved layout: flat index v*512 + u*4 + g, u=hcol 0..127, g=0..3.
// A lane needing gates {i,f,c,o} of hcol u reads ONE 8B word per token.
// ---------------------------------------------------------------------------
#define VROWS 32
__global__ __launch_bounds__(512) void build_P(
    const float* __restrict__ emb, const float* __restrict__ w_ih,
    const float* __restrict__ b_ih, const float* __restrict__ b_hh,
    _Float16* __restrict__ P)
{
  __shared__ __align__(16) float eL[VROWS][NEMB];
  const int tid = threadIdx.x;            // gate col j = tid
  const int v0 = blockIdx.x * VROWS;
  int nrows = VOCAB - v0; if (nrows > VROWS) nrows = VROWS;

  for (int f = tid; f < nrows * NEMB; f += 512)
    eL[f / NEMB][f % NEMB] = emb[(size_t)v0 * NEMB + f];

  float w[NEMB];
  {
    const float* wr = w_ih + (size_t)tid * NEMB;
#pragma unroll
    for (int k = 0; k < NEMB; k++) w[k] = wr[k];
  }
  float bias = b_ih[tid] + b_hh[tid];
  const int pidx = ((tid & 127) << 2) + (tid >> 7);  // u*4 + g
  __syncthreads();

  for (int v = 0; v < nrows; v++) {
    const float4* e4 = (const float4*)&eL[v][0];
    float a = bias;
#pragma unroll
    for (int k = 0; k < NEMB / 4; k++) {
      float4 e = e4[k];
      a += w[4 * k] * e.x + w[4 * k + 1] * e.y + w[4 * k + 2] * e.z + w[4 * k + 3] * e.w;
    }
    P[(size_t)(v0 + v) * G4 + pidx] = (_Float16)a;
  }
}

// ---------------------------------------------------------------------------
// Phase B: MFMA LSTM scan. 32 blocks x 512 threads (8 waves), M=16 batch rows
// per block. Per step: G[16x512] = h[16x128] @ W_hh^T via 16x16x32 f16 MFMA
// (B-frags persistent in VGPRs). Wave w owns gate cols {g*128+16w..+15} for
// g=0..3 -> all 4 gates of an h-col live in ONE lane's 4 accumulators ->
// gates + c-update fully in-register. h double-buffered in LDS (XOR-swizzled
// 16B granules), ONE lgkm-only barrier/step. xg from P' prefetched 2 steps.
// ---------------------------------------------------------------------------
__global__ __launch_bounds__(512, 2) void lstm_mfma(
    const int* __restrict__ x, const float* __restrict__ w_hh,
    const _Float16* __restrict__ P, float* __restrict__ hout)
{
  __shared__ ushort tokL[MTILE * SEQ];                     // 32 KB
  __shared__ __align__(16) _Float16 hbuf[2][MTILE * HID];  // 8 KB

  const int tid  = threadIdx.x;
  const int lane = tid & 63;
  const int wave = tid >> 6;        // 0..7
  const int l15  = lane & 15;
  const int lg   = lane >> 4;       // 0..3
  const int u    = wave * 16 + l15; // hcol 0..127
  const int blk  = blockIdx.x;

  // tokens -> u16 LDS (VOCAB < 65536)
  {
    const int* xp = x + (size_t)blk * MTILE * SEQ;
    for (int i = tid; i < MTILE * SEQ; i += 512) tokL[i] = (ushort)xp[i];
  }
  // zero both h buffers (2*16*128 f16 = 8192B = 512 uint4)
  {
    uint4 z; z.x = z.y = z.z = z.w = 0u;
    ((uint4*)&hbuf[0][0])[tid] = z;
  }

  // B-fragments: Bf[gate][k-chunk]; lane holds W_hh[g*128+u][ck*32+lg*8 .. +7]
  f16x8 Bf[4][4];
#pragma unroll
  for (int n = 0; n < 4; n++) {
    const float* wr = w_hh + (size_t)(n * 128 + u) * HID + lg * 8;
#pragma unroll
    for (int ck = 0; ck < 4; ck++) {
      const float4* p4 = (const float4*)(wr + ck * 32);
      float4 wa = p4[0], wb = p4[1];
      f16x8 f;
      f[0] = (_Float16)wa.x; f[1] = (_Float16)wa.y;
      f[2] = (_Float16)wa.z; f[3] = (_Float16)wa.w;
      f[4] = (_Float16)wb.x; f[5] = (_Float16)wb.y;
      f[6] = (_Float16)wb.z; f[7] = (_Float16)wb.w;
      Bf[n][ck] = f;
    }
  }

  // Precomputed LDS byte offsets (granule = 16B = 8 f16; swizzle g^row).
  int aoff[4], woff[4], toff4[4];
#pragma unroll
  for (int ck = 0; ck < 4; ck++)
    aoff[ck] = l15 * 256 + (((ck * 4 + lg) ^ l15) << 4);
  const int gW = u >> 3;
#pragma unroll
  for (int r = 0; r < 4; r++) {
    int row = lg * 4 + r;           // C/D row mapping: 4*(lane>>4)+reg
    woff[r]  = row * 256 + ((gW ^ row) << 4) + (u & 7) * 2;
    toff4[r] = row * SEQ;
  }

  __syncthreads();  // tokens + zeroed h visible

  float cst[4] = {0.f, 0.f, 0.f, 0.f};

  // prefetch xg for t=0 (A) and t=1 (B): 8B per token-row
  uint2 xgA[4], xgB[4];
#pragma unroll
  for (int r = 0; r < 4; r++) {
    int t0 = tokL[toff4[r] + 0];
    int t1 = tokL[toff4[r] + 1];
    xgA[r] = *(const uint2*)(P + (size_t)t0 * G4 + u * 4);
    xgB[r] = *(const uint2*)(P + (size_t)t1 * G4 + u * 4);
  }

#define STEP(t, par) do {                                                      \
    /* C-init from prefetched xg (i,f,c,o packed per token-row) */             \
    f32x4 ac0, ac1, ac2, ac3;                                                  \
    _Pragma("unroll")                                                          \
    for (int r = 0; r < 4; r++) {                                              \
      uint2 v = (par) ? xgB[r] : xgA[r];                                       \
      half2t p0 = __builtin_bit_cast(half2t, v.x);                             \
      half2t p1 = __builtin_bit_cast(half2t, v.y);                             \
      ac0[r] = (float)p0.x; ac1[r] = (float)p0.y;                              \
      ac2[r] = (float)p1.x; ac3[r] = (float)p1.y;                              \
    }                                                                          \
    /* issue prefetch for t+2 (stays in flight across the barrier) */          \
    {                                                                          \
      int tc = (t) + 2; if (tc > SEQ - 1) tc = SEQ - 1;                        \
      _Pragma("unroll")                                                        \
      for (int r = 0; r < 4; r++) {                                            \
        int tk = tokL[toff4[r] + tc];                                          \
        uint2 v = *(const uint2*)(P + (size_t)tk * G4 + u * 4);                \
        if (par) xgB[r] = v; else xgA[r] = v;                                  \
      }                                                                        \
    }                                                                          \
    /* A-fragments (h) from swizzled LDS, then 16 MFMA (4 gates x 4 K) */      \
    const char* hc = (const char*)&hbuf[(t) & 1][0];                           \
    f16x8 A0 = *(const f16x8*)(hc + aoff[0]);                                  \
    f16x8 A1 = *(const f16x8*)(hc + aoff[1]);                                  \
    f16x8 A2 = *(const f16x8*)(hc + aoff[2]);                                  \
    f16x8 A3 = *(const f16x8*)(hc + aoff[3]);                                  \
    ac0 = __builtin_amdgcn_mfma_f32_16x16x32_f16(A0, Bf[0][0], ac0, 0, 0, 0);  \
    ac1 = __builtin_amdgcn_mfma_f32_16x16x32_f16(A0, Bf[1][0], ac1, 0, 0, 0);  \
    ac2 = __builtin_amdgcn_mfma_f32_16x16x32_f16(A0, Bf[2][0], ac2, 0, 0, 0);  \
    ac3 = __builtin_amdgcn_mfma_f32_16x16x32_f16(A0, Bf[3][0], ac3, 0, 0, 0);  \
    ac0 = __builtin_amdgcn_mfma_f32_16x16x32_f16(A1, Bf[0][1], ac0, 0, 0, 0);  \
    ac1 = __builtin_amdgcn_mfma_f32_16x16x32_f16(A1, Bf[1][1], ac1, 0, 0, 0);  \
    ac2 = __builtin_amdgcn_mfma_f32_16x16x32_f16(A1, Bf[2][1], ac2, 0, 0, 0);  \
    ac3 = __builtin_amdgcn_mfma_f32_16x16x32_f16(A1, Bf[3][1], ac3, 0, 0, 0);  \
    ac0 = __builtin_amdgcn_mfma_f32_16x16x32_f16(A2, Bf[0][2], ac0, 0, 0, 0);  \
    ac1 = __builtin_amdgcn_mfma_f32_16x16x32_f16(A2, Bf[1][2], ac1, 0, 0, 0);  \
    ac2 = __builtin_amdgcn_mfma_f32_16x16x32_f16(A2, Bf[2][2], ac2, 0, 0, 0);  \
    ac3 = __builtin_amdgcn_mfma_f32_16x16x32_f16(A2, Bf[3][2], ac3, 0, 0, 0);  \
    ac0 = __builtin_amdgcn_mfma_f32_16x16x32_f16(A3, Bf[0][3], ac0, 0, 0, 0);  \
    ac1 = __builtin_amdgcn_mfma_f32_16x16x32_f16(A3, Bf[1][3], ac1, 0, 0, 0);  \
    ac2 = __builtin_amdgcn_mfma_f32_16x16x32_f16(A3, Bf[2][3], ac2, 0, 0, 0);  \
    ac3 = __builtin_amdgcn_mfma_f32_16x16x32_f16(A3, Bf[3][3], ac3, 0, 0, 0);  \
    /* gates + c-update fully in-register; h -> other LDS buffer */            \
    char* hn = (char*)&hbuf[((t) + 1) & 1][0];                                 \
    _Pragma("unroll")                                                          \
    for (int r = 0; r < 4; r++) {                                              \
      float iv = sigm(ac0[r]), fv = sigm(ac1[r]);                              \
      float gv = tanhfast(ac2[r]), ov = sigm(ac3[r]);                          \
      cst[r] = fv * cst[r] + iv * gv;                                          \
      float hh = ov * tanhfast(cst[r]);                                        \
      *(_Float16*)(hn + woff[r]) = (_Float16)hh;                               \
      if ((t) == SEQ - 1)                                                      \
        hout[((size_t)blk * MTILE + lg * 4 + r) * HID + u] = hh;               \
    }                                                                          \
    barrier_lds_only();                                                        \
  } while (0)

  for (int t = 0; t < SEQ; t += 2) { STEP(t, 0); STEP(t + 1, 1); }
#undef STEP
}

// ---------------------------------------------------------------------------
// Fallback scan (no workspace for P): R2 structure, one row per block.
// ---------------------------------------------------------------------------
__global__ __launch_bounds__(512, 4) void lstm_scan_fb(
    const int* __restrict__ x, const float* __restrict__ emb,
    const float* __restrict__ w_ih, const float* __restrict__ w_hh,
    const float* __restrict__ b_ih, const float* __restrict__ b_hh,
    float* __restrict__ hout)
{
  __shared__ int tokL[SEQ];
  __shared__ __align__(16) _Float16 h16[HID];
  __shared__ float g2h[2][G4];
  __shared__ __align__(8) half2t e16[2][NEMB / 2];

  const int tid = threadIdx.x;
  const int b = blockIdx.x;
  const int col = tid & 255;
  const int kh = tid >> 8;
  const int koff = kh * (HID / 2);

  {
    const int* xp = x + (size_t)b * SEQ;
#pragma unroll
    for (int i = 0; i < SEQ / 512; i++) tokL[tid + 512 * i] = xp[tid + 512 * i];
  }

  half2t w0[HID / 4], w1[HID / 4];
  {
    const float4* wr0 = (const float4*)(w_hh + (size_t)col * HID + koff);
    const float4* wr1 = (const float4*)(w_hh + (size_t)(col + 256) * HID + koff);
#pragma unroll
    for (int k = 0; k < HID / 8; k++) {
      float4 a = wr0[k];
      half2t p; p.x = (_Float16)a.x; p.y = (_Float16)a.y; w0[2 * k] = p;
      p.x = (_Float16)a.z; p.y = (_Float16)a.w; w0[2 * k + 1] = p;
      float4 bv = wr1[k];
      p.x = (_Float16)bv.x; p.y = (_Float16)bv.y; w1[2 * k] = p;
      p.x = (_Float16)bv.z; p.y = (_Float16)bv.w; w1[2 * k + 1] = p;
    }
  }
  half2t wih0[NEMB / 2], wih1[NEMB / 2];
  float bias0 = 0.0f, bias1 = 0.0f;
  if (kh == 0) {
    const float* wr0 = w_ih + (size_t)col * NEMB;
    const float* wr1 = w_ih + (size_t)(col + 256) * NEMB;
#pragma unroll
    for (int k = 0; k < NEMB / 2; k++) {
      half2t p;
      p.x = (_Float16)wr0[2 * k]; p.y = (_Float16)wr0[2 * k + 1]; wih0[k] = p;
      p.x = (_Float16)wr1[2 * k]; p.y = (_Float16)wr1[2 * k + 1]; wih1[k] = p;
    }
    bias0 = b_ih[col] + b_hh[col];
    bias1 = b_ih[col + 256] + b_hh[col + 256];
  }
  if (tid < HID) h16[tid] = (_Float16)0.0f;
  __syncthreads();

  float c = 0.0f;
  float2 einfl = {0.0f, 0.0f};
  if (tid < NEMB / 2) {
    float2 e0 = ((const float2*)(emb + (size_t)tokL[0] * NEMB))[tid];
    einfl    = ((const float2*)(emb + (size_t)tokL[1] * NEMB))[tid];
    half2t p; p.x = (_Float16)e0.x; p.y = (_Float16)e0.y;
    e16[0][tid] = p;
  }
  __syncthreads();

#define STEPF(t, par) do {                                                     \
    float xg0, xg1;                                                            \
    if (tid < NEMB / 2) {                                                      \
      int tc = (t) + 2; if (tc > SEQ - 1) tc = SEQ - 1;                        \
      half2t p; p.x = (_Float16)einfl.x; p.y = (_Float16)einfl.y;              \
      e16[((t) + 1) & 1][tid] = p;                                             \
      einfl = ((const float2*)(emb + (size_t)tokL[tc] * NEMB))[tid];           \
    }                                                                          \
    if (kh == 0) {                                                             \
      xg0 = bias0; xg1 = bias1;                                                \
      _Pragma("unroll")                                                        \
      for (int k = 0; k < NEMB / 2; k++) {                                     \
        xg0 = fdot2(wih0[k], e16[(par)][k], xg0);                              \
        xg1 = fdot2(wih1[k], e16[(par)][k], xg1);                              \
      }                                                                        \
    } else { xg0 = 0.0f; xg1 = 0.0f; }                                         \
    const uint4* hv = (const uint4*)h16 + (kh << 3);                           \
    float s0 = xg0, u0 = 0.0f, s1 = xg1, u1 = 0.0f;                            \
    _Pragma("unroll")                                                          \
    for (int kt = 0; kt < HID / 16; kt++) {                                    \
      uint4 hq = hv[kt];                                                       \
      half2t ha = __builtin_bit_cast(half2t, hq.x);                            \
      half2t hb = __builtin_bit_cast(half2t, hq.y);                            \
      half2t hc = __builtin_bit_cast(half2t, hq.z);                            \
      half2t hd = __builtin_bit_cast(half2t, hq.w);                            \
      s0 = fdot2(w0[4 * kt + 0], ha, s0);                                      \
      u0 = fdot2(w0[4 * kt + 1], hb, u0);                                      \
      s0 = fdot2(w0[4 * kt + 2], hc, s0);                                      \
      u0 = fdot2(w0[4 * kt + 3], hd, u0);                                      \
      s1 = fdot2(w1[4 * kt + 0], ha, s1);                                      \
      u1 = fdot2(w1[4 * kt + 1], hb, u1);                                      \
      s1 = fdot2(w1[4 * kt + 2], hc, s1);                                      \
      u1 = fdot2(w1[4 * kt + 3], hd, u1);                                      \
    }                                                                          \
    g2h[kh][col] = s0 + u0;                                                    \
    g2h[kh][col + 256] = s1 + u1;                                              \
    barrier_lds_only();                                                        \
    if (tid < HID) {                                                           \
      float gi = g2h[0][tid]           + g2h[1][tid];                          \
      float gf = g2h[0][HID + tid]     + g2h[1][HID + tid];                    \
      float gc = g2h[0][2 * HID + tid] + g2h[1][2 * HID + tid];                \
      float go = g2h[0][3 * HID + tid] + g2h[1][3 * HID + tid];                \
      float fi = sigm(gi), ff = sigm(gf), gt = tanhfast(gc), fo = sigm(go);    \
      c = ff * c + fi * gt;                                                    \
      float hh = fo * tanhfast(c);                                             \
      h16[tid] = (_Float16)hh;                                                 \
      if ((t) == SEQ - 1) hout[(size_t)b * HID + tid] = hh;                    \
    }                                                                          \
    barrier_lds_only();                                                        \
  } while (0)

  for (int t = 0; t < SEQ; t += 2) { STEPF(t, 0); STEPF(t + 1, 1); }
#undef STEPF
}

// ---------------------------------------------------------------------------
// Phase C: FC  out[512,2000] = h[512,128] @ w_fc^T + b_fc.
// ---------------------------------------------------------------------------
#define FCR 64
#define FCC 64
__global__ __launch_bounds__(256) void fc_kernel(
    const float* __restrict__ h, const float* __restrict__ w_fc,
    const float* __restrict__ b_fc, float* __restrict__ out)
{
  __shared__ float aT[HID][FCR];
  __shared__ float bT[HID][FCC];
  const int tid = threadIdx.x;
  const int r0 = blockIdx.y * FCR;
  const int c0 = blockIdx.x * FCC;

  for (int f = tid; f < FCR * (HID / 4); f += 256) {
    int row = f >> 5, q = f & 31;
    float4 v = ((const float4*)h)[(((size_t)(r0 + row)) << 5) + q];
    aT[4 * q + 0][row] = v.x; aT[4 * q + 1][row] = v.y;
    aT[4 * q + 2][row] = v.z; aT[4 * q + 3][row] = v.w;
    int wrow = c0 + row;
    float4 wv;
    if (wrow < NCLS) wv = ((const float4*)w_fc)[(((size_t)wrow) << 5) + q];
    else { wv.x = 0.f; wv.y = 0.f; wv.z = 0.f; wv.w = 0.f; }
    bT[4 * q + 0][row] = wv.x; bT[4 * q + 1][row] = wv.y;
    bT[4 * q + 2][row] = wv.z; bT[4 * q + 3][row] = wv.w;
  }
  __syncthreads();

  const int cr = tid & 15, rr = tid >> 4;
  float acc[4][4];
#pragma unroll
  for (int i = 0; i < 4; i++)
#pragma unroll
    for (int j = 0; j < 4; j++) acc[i][j] = 0.0f;

#pragma unroll 4
  for (int k = 0; k < HID; k++) {
    float4 av = *(const float4*)&aT[k][4 * rr];
    float4 bv = *(const float4*)&bT[k][4 * cr];
    float a[4] = {av.x, av.y, av.z, av.w};
    float bb[4] = {bv.x, bv.y, bv.z, bv.w};
#pragma unroll
    for (int i = 0; i < 4; i++)
#pragma unroll
      for (int j = 0; j < 4; j++) acc[i][j] += a[i] * bb[j];
  }

#pragma unroll
  for (int j = 0; j < 4; j++) {
    int cc = c0 + 4 * cr + j;
    if (cc < NCLS) {
      float bias = b_fc[cc];
#pragma unroll
      for (int i = 0; i < 4; i++)
        out[(size_t)(r0 + 4 * rr + i) * NCLS + cc] = acc[i][j] + bias;
    }
  }
}

extern "C" void kernel_launch(void* const* d_in, const int* in_sizes, int n_in,
                              void* d_out, int out_size, void* d_ws, size_t ws_size,
                              hipStream_t stream) {
  const int*   xx   = (const int*)d_in[0];
  const float* emb  = (const float*)d_in[1];
  const float* w_ih = (const float*)d_in[2];
  const float* w_hh = (const float*)d_in[3];
  const float* b_ih = (const float*)d_in[4];
  const float* b_hh = (const float*)d_in[5];
  const float* w_fc = (const float*)d_in[6];
  const float* b_fc = (const float*)d_in[7];
  float* out = (float*)d_out;

  const size_t pbytes = (size_t)VOCAB * G4 * sizeof(_Float16); // 51.5 MB
  const size_t palign = (pbytes + 255) & ~(size_t)255;
  const size_t hbytes = (size_t)BATCH * HID * sizeof(float);

  float* hout;
  if (ws_size >= palign + hbytes) {
    _Float16* P = (_Float16*)d_ws;
    hout = (float*)((char*)d_ws + palign);
    build_P<<<(VOCAB + VROWS - 1) / VROWS, 512, 0, stream>>>(emb, w_ih, b_ih, b_hh, P);
    lstm_mfma<<<NBLK, 512, 0, stream>>>(xx, w_hh, P, hout);
  } else {
    hout = (float*)d_ws;
    lstm_scan_fb<<<BATCH, 512, 0, stream>>>(xx, emb, w_ih, w_hh, b_ih, b_hh, hout);
  }
  dim3 fcg((NCLS + FCC - 1) / FCC, BATCH / FCR);
  fc_kernel<<<fcg, 256, 0, stream>>>(hout, w_fc, b_fc, out);
}

// Round 6
// 916.150 us; speedup vs baseline: 1.2248x; 1.1645x over previous
//
#include <hip/hip_runtime.h>

#define DI __device__ __forceinline__

typedef unsigned int uint;
typedef unsigned short ushort;
typedef _Float16 half2t __attribute__((ext_vector_type(2)));
typedef _Float16 f16x8 __attribute__((ext_vector_type(8)));
typedef float f32x4 __attribute__((ext_vector_type(4)));

#define VOCAB 50257
#define NEMB 48
#define HID 128
#define G4 512
#define NCLS 2000
#define BATCH 512
#define SEQ 1024
#define MROWS 2
#define NBLK2 (BATCH / MROWS)   // 256 blocks -> 1 per CU

DI float sigm(float x) {
  return __builtin_amdgcn_rcpf(1.0f + __builtin_amdgcn_exp2f(-1.4426950408889634f * x));
}
DI float tanhfast(float x) {
  return 1.0f - 2.0f * __builtin_amdgcn_rcpf(__builtin_amdgcn_exp2f(2.8853900817779268f * x) + 1.0f);
}

// Barrier draining ONLY LDS (lgkmcnt); global-load prefetches (vmcnt) stay
// in flight across it.
DI void barrier_lds_only() {
  asm volatile("s_waitcnt lgkmcnt(0)" ::: "memory");
  __builtin_amdgcn_s_barrier();
  asm volatile("" ::: "memory");
}

// ---------------------------------------------------------------------------
// Phase A: P'[v][u][g] = emb[v] . w_ih[g*128+u] + b_ih + b_hh   (f16 out)
// Gate-interleaved: flat v*512 + u*4 + g  (u = hcol, g = i,f,c,o).
// A gate thread reads ONE 8B word per token = all 4 gate xg's of its hcol.
// ---------------------------------------------------------------------------
#define VROWS 32
__global__ __launch_bounds__(512) void build_P(
    const float* __restrict__ emb, const float* __restrict__ w_ih,
    const float* __restrict__ b_ih, const float* __restrict__ b_hh,
    _Float16* __restrict__ P)
{
  __shared__ __align__(16) float eL[VROWS][NEMB];
  const int tid = threadIdx.x;            // gate col j = tid
  const int v0 = blockIdx.x * VROWS;
  int nrows = VOCAB - v0; if (nrows > VROWS) nrows = VROWS;

  for (int f = tid; f < nrows * NEMB; f += 512)
    eL[f / NEMB][f % NEMB] = emb[(size_t)v0 * NEMB + f];

  float w[NEMB];
  {
    const float* wr = w_ih + (size_t)tid * NEMB;
#pragma unroll
    for (int k = 0; k < NEMB; k++) w[k] = wr[k];
  }
  float bias = b_ih[tid] + b_hh[tid];
  const int pidx = ((tid & 127) << 2) + (tid >> 7);  // u*4 + g
  __syncthreads();

  for (int v = 0; v < nrows; v++) {
    const float4* e4 = (const float4*)&eL[v][0];
    float a = bias;
#pragma unroll
    for (int k = 0; k < NEMB / 4; k++) {
      float4 e = e4[k];
      a += w[4 * k] * e.x + w[4 * k + 1] * e.y + w[4 * k + 2] * e.z + w[4 * k + 3] * e.w;
    }
    P[(size_t)(v0 + v) * G4 + pidx] = (_Float16)a;
  }
}

// ---------------------------------------------------------------------------
// Phase B: MFMA LSTM scan, M=2 rows/block x 256 blocks (full chip).
// 512 threads (8 waves). Per step: G[2x512] = h[2x128] @ W_hh^T via 16 MFMA
// per wave (wave w owns gate cols w*64..w*64+63; M-rows 2..15 of the MFMA
// are zero padding -> dead C rows, never read). Live C rows 0,1 (lanes
// lg==0, regs 0,1) -> LDS float2 pairs; gate phase runs DENSE on tid<256
// (1 output/lane). xg prefetched 2 steps deep; CURRENT xg captured into
// xcur BEFORE the prefetch overwrites the register (the R5 bug).
// ---------------------------------------------------------------------------
__global__ __launch_bounds__(512, 2) void lstm_mfma2(
    const int* __restrict__ x, const float* __restrict__ w_hh,
    const _Float16* __restrict__ P, float* __restrict__ hout)
{
  __shared__ ushort tokL[MROWS][SEQ];                   // 4 KB
  __shared__ __align__(16) _Float16 hbuf[16][HID];      // 4 KB, rows 2..15 stay 0
  __shared__ __align__(8) float2 gpair[G4];             // 4 KB, [gatecol]={row0,row1}

  const int tid  = threadIdx.x;
  const int lane = tid & 63;
  const int wave = tid >> 6;        // 0..7
  const int l15  = lane & 15;
  const int lg   = lane >> 4;       // 0..3
  const int blk  = blockIdx.x;

  // stage tokens as u16 (VOCAB < 65536)
  {
    const int* xp = x + (size_t)blk * MROWS * SEQ;
    for (int i = tid; i < MROWS * SEQ; i += 512) ((ushort*)tokL)[i] = (ushort)xp[i];
  }
  // zero hbuf (16*128 f16 = 4KB)
  for (int i = tid; i < 16 * HID / 2; i += 512) ((uint*)hbuf)[i] = 0u;

  // B fragments: wave w owns gate cols j = w*64 + tau*16 + l15, tau=0..3.
  // Lane holds W_hh[j][ck*32 + lg*8 .. +7] per K-chunk ck (same k-map as A).
  f16x8 Bf[4][4];
#pragma unroll
  for (int tau = 0; tau < 4; tau++) {
    const float* wr = w_hh + (size_t)(wave * 64 + tau * 16 + l15) * HID + lg * 8;
#pragma unroll
    for (int ck = 0; ck < 4; ck++) {
      const float4* p4 = (const float4*)(wr + ck * 32);
      float4 wa = p4[0], wb = p4[1];
      f16x8 f;
      f[0] = (_Float16)wa.x; f[1] = (_Float16)wa.y;
      f[2] = (_Float16)wa.z; f[3] = (_Float16)wa.w;
      f[4] = (_Float16)wb.x; f[5] = (_Float16)wb.y;
      f[6] = (_Float16)wb.z; f[7] = (_Float16)wb.w;
      Bf[tau][ck] = f;
    }
  }

  // A-read offsets: row=l15, granule (ck*4+lg), XOR-swizzled within row.
  int aoff[4];
#pragma unroll
  for (int ck = 0; ck < 4; ck++)
    aoff[ck] = l15 * 256 + ((((ck * 4 + lg) ^ l15)) << 4);

  // gate-thread constants (valid when tid < 256)
  const int grow = tid >> 7;        // batch row 0/1
  const int gcol = tid & 127;       // hcol
  const int gbase = gcol * 2 + grow;                       // float idx into gpair
  const int hwoff = grow * 256 + (((gcol >> 3) ^ grow) << 4) + (gcol & 7) * 2;
  float cst = 0.0f;

  __syncthreads();  // tokens + zeroed hbuf visible

  uint2 xgA = {0, 0}, xgB = {0, 0};
  if (tid < 256) {
    int t0 = tokL[grow][0], t1 = tokL[grow][1];
    xgA = *(const uint2*)(P + (size_t)t0 * G4 + gcol * 4);
    xgB = *(const uint2*)(P + (size_t)t1 * G4 + gcol * 4);
  }

  const f32x4 fz = {0.f, 0.f, 0.f, 0.f};
  const char* hB = (const char*)hbuf;

#define MF(Areg, ckk, a0, a1, a2, a3) do {                                     \
    a0 = __builtin_amdgcn_mfma_f32_16x16x32_f16(Areg, Bf[0][ckk], a0, 0, 0, 0);\
    a1 = __builtin_amdgcn_mfma_f32_16x16x32_f16(Areg, Bf[1][ckk], a1, 0, 0, 0);\
    a2 = __builtin_amdgcn_mfma_f32_16x16x32_f16(Areg, Bf[2][ckk], a2, 0, 0, 0);\
    a3 = __builtin_amdgcn_mfma_f32_16x16x32_f16(Areg, Bf[3][ckk], a3, 0, 0, 0);\
  } while (0)

#define STEP(t, par) do {                                                      \
    f16x8 A0 = *(const f16x8*)(hB + aoff[0]);                                  \
    f16x8 A1 = *(const f16x8*)(hB + aoff[1]);                                  \
    f16x8 A2 = *(const f16x8*)(hB + aoff[2]);                                  \
    f16x8 A3 = *(const f16x8*)(hB + aoff[3]);                                  \
    f32x4 a0 = fz, a1 = fz, a2 = fz, a3 = fz;                                  \
    MF(A0, 0, a0, a1, a2, a3);                                                 \
    MF(A1, 1, a0, a1, a2, a3);                                                 \
    MF(A2, 2, a0, a1, a2, a3);                                                 \
    MF(A3, 3, a0, a1, a2, a3);                                                 \
    uint2 xcur = {0, 0};                                                       \
    if (tid < 256) {                                                           \
      xcur = (par) ? xgB : xgA;   /* capture CURRENT xg before overwrite */    \
      int tc = (t) + 2; if (tc > SEQ - 1) tc = SEQ - 1;                        \
      int tk = tokL[grow][tc];                                                 \
      uint2 v = *(const uint2*)(P + (size_t)tk * G4 + gcol * 4);               \
      if (par) xgB = v; else xgA = v;                                          \
    }                                                                          \
    if (lg == 0) { /* live C rows 0,1 at lanes l15; col = wave*64+tau*16+l15 */\
      float2 p;                                                                \
      p.x = a0[0]; p.y = a0[1]; gpair[wave * 64 +  0 + l15] = p;               \
      p.x = a1[0]; p.y = a1[1]; gpair[wave * 64 + 16 + l15] = p;               \
      p.x = a2[0]; p.y = a2[1]; gpair[wave * 64 + 32 + l15] = p;               \
      p.x = a3[0]; p.y = a3[1]; gpair[wave * 64 + 48 + l15] = p;               \
    }                                                                          \
    barrier_lds_only();                                                        \
    if (tid < 256) {                                                           \
      half2t x0 = __builtin_bit_cast(half2t, xcur.x);                          \
      half2t x1 = __builtin_bit_cast(half2t, xcur.y);                          \
      const float* gp = (const float*)gpair;                                   \
      float gi = gp[gbase]       + (float)x0.x;                                \
      float gf = gp[gbase + 256] + (float)x0.y;                                \
      float gc = gp[gbase + 512] + (float)x1.x;                                \
      float go = gp[gbase + 768] + (float)x1.y;                                \
      float fi = sigm(gi), ff = sigm(gf), gt = tanhfast(gc), fo = sigm(go);    \
      cst = ff * cst + fi * gt;                                                \
      float hh = fo * tanhfast(cst);                                           \
      *(_Float16*)((char*)hbuf + hwoff) = (_Float16)hh;                        \
      if ((t) == SEQ - 1)                                                      \
        hout[((size_t)blk * MROWS + grow) * HID + gcol] = hh;                  \
    }                                                                          \
    barrier_lds_only();                                                        \
  } while (0)

  for (int t = 0; t < SEQ; t += 2) { STEP(t, 0); STEP(t + 1, 1); }
#undef STEP
#undef MF
}

// ---------------------------------------------------------------------------
// Fallback scan (no workspace for P): one row per block, fma path.
// ---------------------------------------------------------------------------
typedef _Float16 h2 __attribute__((ext_vector_type(2)));
DI float fdot2f(h2 a, h2 b, float c) { return c + (float)a.x * (float)b.x + (float)a.y * (float)b.y; }

__global__ __launch_bounds__(512, 4) void lstm_scan_fb(
    const int* __restrict__ x, const float* __restrict__ emb,
    const float* __restrict__ w_ih, const float* __restrict__ w_hh,
    const float* __restrict__ b_ih, const float* __restrict__ b_hh,
    float* __restrict__ hout)
{
  __shared__ int tokL[SEQ];
  __shared__ __align__(16) _Float16 h16[HID];
  __shared__ float g2h[2][G4];
  __shared__ __align__(8) h2 e16[2][NEMB / 2];

  const int tid = threadIdx.x;
  const int b = blockIdx.x;
  const int col = tid & 255;
  const int kh = tid >> 8;
  const int koff = kh * (HID / 2);

  {
    const int* xp = x + (size_t)b * SEQ;
#pragma unroll
    for (int i = 0; i < SEQ / 512; i++) tokL[tid + 512 * i] = xp[tid + 512 * i];
  }

  h2 w0[HID / 4], w1[HID / 4];
  {
    const float4* wr0 = (const float4*)(w_hh + (size_t)col * HID + koff);
    const float4* wr1 = (const float4*)(w_hh + (size_t)(col + 256) * HID + koff);
#pragma unroll
    for (int k = 0; k < HID / 8; k++) {
      float4 a = wr0[k];
      h2 p; p.x = (_Float16)a.x; p.y = (_Float16)a.y; w0[2 * k] = p;
      p.x = (_Float16)a.z; p.y = (_Float16)a.w; w0[2 * k + 1] = p;
      float4 bv = wr1[k];
      p.x = (_Float16)bv.x; p.y = (_Float16)bv.y; w1[2 * k] = p;
      p.x = (_Float16)bv.z; p.y = (_Float16)bv.w; w1[2 * k + 1] = p;
    }
  }
  h2 wih0[NEMB / 2], wih1[NEMB / 2];
  float bias0 = 0.0f, bias1 = 0.0f;
  if (kh == 0) {
    const float* wr0 = w_ih + (size_t)col * NEMB;
    const float* wr1 = w_ih + (size_t)(col + 256) * NEMB;
#pragma unroll
    for (int k = 0; k < NEMB / 2; k++) {
      h2 p;
      p.x = (_Float16)wr0[2 * k]; p.y = (_Float16)wr0[2 * k + 1]; wih0[k] = p;
      p.x = (_Float16)wr1[2 * k]; p.y = (_Float16)wr1[2 * k + 1]; wih1[k] = p;
    }
    bias0 = b_ih[col] + b_hh[col];
    bias1 = b_ih[col + 256] + b_hh[col + 256];
  }
  if (tid < HID) h16[tid] = (_Float16)0.0f;
  __syncthreads();

  float c = 0.0f;
  float2 einfl = {0.0f, 0.0f};
  if (tid < NEMB / 2) {
    float2 e0 = ((const float2*)(emb + (size_t)tokL[0] * NEMB))[tid];
    einfl    = ((const float2*)(emb + (size_t)tokL[1] * NEMB))[tid];
    h2 p; p.x = (_Float16)e0.x; p.y = (_Float16)e0.y;
    e16[0][tid] = p;
  }
  __syncthreads();

#define STEPF(t, par) do {                                                     \
    float xg0, xg1;                                                            \
    if (tid < NEMB / 2) {                                                      \
      int tc = (t) + 2; if (tc > SEQ - 1) tc = SEQ - 1;                        \
      h2 p; p.x = (_Float16)einfl.x; p.y = (_Float16)einfl.y;                  \
      e16[((t) + 1) & 1][tid] = p;                                             \
      einfl = ((const float2*)(emb + (size_t)tokL[tc] * NEMB))[tid];           \
    }                                                                          \
    if (kh == 0) {                                                             \
      xg0 = bias0; xg1 = bias1;                                                \
      _Pragma("unroll")                                                        \
      for (int k = 0; k < NEMB / 2; k++) {                                     \
        xg0 = fdot2f(wih0[k], e16[(par)][k], xg0);                             \
        xg1 = fdot2f(wih1[k], e16[(par)][k], xg1);                             \
      }                                                                        \
    } else { xg0 = 0.0f; xg1 = 0.0f; }                                         \
    const uint4* hv = (const uint4*)h16 + (kh << 3);                           \
    float s0 = xg0, u0 = 0.0f, s1 = xg1, u1 = 0.0f;                            \
    _Pragma("unroll")                                                          \
    for (int kt = 0; kt < HID / 16; kt++) {                                    \
      uint4 hq = hv[kt];                                                       \
      h2 ha = __builtin_bit_cast(h2, hq.x);                                    \
      h2 hb = __builtin_bit_cast(h2, hq.y);                                    \
      h2 hc = __builtin_bit_cast(h2, hq.z);                                    \
      h2 hd = __builtin_bit_cast(h2, hq.w);                                    \
      s0 = fdot2f(w0[4 * kt + 0], ha, s0);                                     \
      u0 = fdot2f(w0[4 * kt + 1], hb, u0);                                     \
      s0 = fdot2f(w0[4 * kt + 2], hc, s0);                                     \
      u0 = fdot2f(w0[4 * kt + 3], hd, u0);                                     \
      s1 = fdot2f(w1[4 * kt + 0], ha, s1);                                     \
      u1 = fdot2f(w1[4 * kt + 1], hb, u1);                                     \
      s1 = fdot2f(w1[4 * kt + 2], hc, s1);                                     \
      u1 = fdot2f(w1[4 * kt + 3], hd, u1);                                     \
    }                                                                          \
    g2h[kh][col] = s0 + u0;                                                    \
    g2h[kh][col + 256] = s1 + u1;                                              \
    barrier_lds_only();                                                        \
    if (tid < HID) {                                                           \
      float gi = g2h[0][tid]           + g2h[1][tid];                          \
      float gf = g2h[0][HID + tid]     + g2h[1][HID + tid];                    \
      float gc = g2h[0][2 * HID + tid] + g2h[1][2 * HID + tid];                \
      float go = g2h[0][3 * HID + tid] + g2h[1][3 * HID + tid];                \
      float fi = sigm(gi), ff = sigm(gf), gt = tanhfast(gc), fo = sigm(go);    \
      c = ff * c + fi * gt;                                                    \
      float hh = fo * tanhfast(c);                                             \
      h16[tid] = (_Float16)hh;                                                 \
      if ((t) == SEQ - 1) hout[(size_t)b * HID + tid] = hh;                    \
    }                                                                          \
    barrier_lds_only();                                                        \
  } while (0)

  for (int t = 0; t < SEQ; t += 2) { STEPF(t, 0); STEPF(t + 1, 1); }
#undef STEPF
}

// ---------------------------------------------------------------------------
// Phase C: FC  out[512,2000] = h[512,128] @ w_fc^T + b_fc.
// ---------------------------------------------------------------------------
#define FCR 64
#define FCC 64
__global__ __launch_bounds__(256) void fc_kernel(
    const float* __restrict__ h, const float* __restrict__ w_fc,
    const float* __restrict__ b_fc, float* __restrict__ out)
{
  __shared__ float aT[HID][FCR];
  __shared__ float bT[HID][FCC];
  const int tid = threadIdx.x;
  const int r0 = blockIdx.y * FCR;
  const int c0 = blockIdx.x * FCC;

  for (int f = tid; f < FCR * (HID / 4); f += 256) {
    int row = f >> 5, q = f & 31;
    float4 v = ((const float4*)h)[(((size_t)(r0 + row)) << 5) + q];
    aT[4 * q + 0][row] = v.x; aT[4 * q + 1][row] = v.y;
    aT[4 * q + 2][row] = v.z; aT[4 * q + 3][row] = v.w;
    int wrow = c0 + row;
    float4 wv;
    if (wrow < NCLS) wv = ((const float4*)w_fc)[(((size_t)wrow) << 5) + q];
    else { wv.x = 0.f; wv.y = 0.f; wv.z = 0.f; wv.w = 0.f; }
    bT[4 * q + 0][row] = wv.x; bT[4 * q + 1][row] = wv.y;
    bT[4 * q + 2][row] = wv.z; bT[4 * q + 3][row] = wv.w;
  }
  __syncthreads();

  const int cr = tid & 15, rr = tid >> 4;
  float acc[4][4];
#pragma unroll
  for (int i = 0; i < 4; i++)
#pragma unroll
    for (int j = 0; j < 4; j++) acc[i][j] = 0.0f;

#pragma unroll 4
  for (int k = 0; k < HID; k++) {
    float4 av = *(const float4*)&aT[k][4 * rr];
    float4 bv = *(const float4*)&bT[k][4 * cr];
    float a[4] = {av.x, av.y, av.z, av.w};
    float bb[4] = {bv.x, bv.y, bv.z, bv.w};
#pragma unroll
    for (int i = 0; i < 4; i++)
#pragma unroll
      for (int j = 0; j < 4; j++) acc[i][j] += a[i] * bb[j];
  }

#pragma unroll
  for (int j = 0; j < 4; j++) {
    int cc = c0 + 4 * cr + j;
    if (cc < NCLS) {
      float bias = b_fc[cc];
#pragma unroll
      for (int i = 0; i < 4; i++)
        out[(size_t)(r0 + 4 * rr + i) * NCLS + cc] = acc[i][j] + bias;
    }
  }
}

extern "C" void kernel_launch(void* const* d_in, const int* in_sizes, int n_in,
                              void* d_out, int out_size, void* d_ws, size_t ws_size,
                              hipStream_t stream) {
  const int*   xx   = (const int*)d_in[0];
  const float* emb  = (const float*)d_in[1];
  const float* w_ih = (const float*)d_in[2];
  const float* w_hh = (const float*)d_in[3];
  const float* b_ih = (const float*)d_in[4];
  const float* b_hh = (const float*)d_in[5];
  const float* w_fc = (const float*)d_in[6];
  const float* b_fc = (const float*)d_in[7];
  float* out = (float*)d_out;

  const size_t pbytes = (size_t)VOCAB * G4 * sizeof(_Float16); // 51.5 MB
  const size_t palign = (pbytes + 255) & ~(size_t)255;
  const size_t hbytes = (size_t)BATCH * HID * sizeof(float);

  float* hout;
  if (ws_size >= palign + hbytes) {
    _Float16* P = (_Float16*)d_ws;
    hout = (float*)((char*)d_ws + palign);
    build_P<<<(VOCAB + VROWS - 1) / VROWS, 512, 0, stream>>>(emb, w_ih, b_ih, b_hh, P);
    lstm_mfma2<<<NBLK2, 512, 0, stream>>>(xx, w_hh, P, hout);
  } else {
    hout = (float*)d_ws;
    lstm_scan_fb<<<BATCH, 512, 0, stream>>>(xx, emb, w_ih, w_hh, b_ih, b_hh, hout);
  }
  dim3 fcg((NCLS + FCC - 1) / FCC, BATCH / FCR);
  fc_kernel<<<fcg, 256, 0, stream>>>(hout, w_fc, b_fc, out);
}

// Round 8
// 869.035 us; speedup vs baseline: 1.2912x; 1.0542x over previous
//
#include <hip/hip_runtime.h>

#define DI __device__ __forceinline__

typedef unsigned int uint;
typedef unsigned short ushort;
typedef _Float16 half2t __attribute__((ext_vector_type(2)));
typedef _Float16 f16x8 __attribute__((ext_vector_type(8)));
typedef float f32x4 __attribute__((ext_vector_type(4)));

#define VOCAB 50257
#define NEMB 48
#define HID 128
#define G4 512
#define NCLS 2000
#define BATCH 512
#define SEQ 1024
#define MROWS 2
#define NBLK2 (BATCH / MROWS)   // 256 blocks -> 1 per CU

DI float sigm(float x) {
  return __builtin_amdgcn_rcpf(1.0f + __builtin_amdgcn_exp2f(-1.4426950408889634f * x));
}
DI float tanhfast(float x) {
  return 1.0f - 2.0f * __builtin_amdgcn_rcpf(__builtin_amdgcn_exp2f(2.8853900817779268f * x) + 1.0f);
}

// Barrier draining ONLY LDS (lgkmcnt); global-load prefetches (vmcnt) stay
// in flight across it.
DI void barrier_lds_only() {
  asm volatile("s_waitcnt lgkmcnt(0)" ::: "memory");
  __builtin_amdgcn_s_barrier();
  asm volatile("" ::: "memory");
}

// ---------------------------------------------------------------------------
// Phase A: P'[v][u][g] = emb[v] . w_ih[g*128+u] + b_ih + b_hh   (f16 out)
// Gate-interleaved: flat v*512 + u*4 + g  (u = hcol, g = i,f,c,o).
// ---------------------------------------------------------------------------
#define VROWS 32
__global__ __launch_bounds__(512) void build_P(
    const float* __restrict__ emb, const float* __restrict__ w_ih,
    const float* __restrict__ b_ih, const float* __restrict__ b_hh,
    _Float16* __restrict__ P)
{
  __shared__ __align__(16) float eL[VROWS][NEMB];
  const int tid = threadIdx.x;            // gate col j = tid
  const int v0 = blockIdx.x * VROWS;
  int nrows = VOCAB - v0; if (nrows > VROWS) nrows = VROWS;

  for (int f = tid; f < nrows * NEMB; f += 512)
    eL[f / NEMB][f % NEMB] = emb[(size_t)v0 * NEMB + f];

  float w[NEMB];
  {
    const float* wr = w_ih + (size_t)tid * NEMB;
#pragma unroll
    for (int k = 0; k < NEMB; k++) w[k] = wr[k];
  }
  float bias = b_ih[tid] + b_hh[tid];
  const int pidx = ((tid & 127) << 2) + (tid >> 7);  // u*4 + g
  __syncthreads();

  for (int v = 0; v < nrows; v++) {
    const float4* e4 = (const float4*)&eL[v][0];
    float a = bias;
#pragma unroll
    for (int k = 0; k < NEMB / 4; k++) {
      float4 e = e4[k];
      a += w[4 * k] * e.x + w[4 * k + 1] * e.y + w[4 * k + 2] * e.z + w[4 * k + 3] * e.w;
    }
    P[(size_t)(v0 + v) * G4 + pidx] = (_Float16)a;
  }
}

// ---------------------------------------------------------------------------
// Phase B: MFMA LSTM scan, fused gates, NO cross-lane ops. M=2 rows/block x
// 256 blocks, 512 threads (8 waves). Wave w owns all four gates of hcols
// w*16..w*16+15: Bf[g] = W_hh rows g*128 + u. C layout (col=lane&15,
// row=4*lg+reg): lanes lg==0 hold batch row 0 in reg 0 AND batch row 1 in
// reg 1 (R6-verified extraction) -> they compute BOTH rows' gates
// in-register (cst0/cst1) and write both h f16 values. Double-buffered
// hbuf[2] + ONE lgkm-only barrier per step (R4-verified skeleton).
// xg prefetched 2 steps deep, captured before overwrite (R5 lesson).
// ---------------------------------------------------------------------------
__global__ __launch_bounds__(512, 2) void lstm_mfma4(
    const int* __restrict__ x, const float* __restrict__ w_hh,
    const _Float16* __restrict__ P, float* __restrict__ hout)
{
  __shared__ ushort tokL[MROWS][SEQ];                     // 4 KB
  __shared__ __align__(16) _Float16 hbuf[2][16][HID];     // 8 KB, rows 2..15 stay 0

  const int tid  = threadIdx.x;
  const int lane = tid & 63;
  const int wave = tid >> 6;        // 0..7
  const int l15  = lane & 15;
  const int lg   = lane >> 4;       // 0..3
  const int u    = wave * 16 + l15; // hcol this lane owns (gates, lg==0 only)
  const int blk  = blockIdx.x;

  // stage tokens as u16 (VOCAB < 65536)
  {
    const int* xp = x + (size_t)blk * MROWS * SEQ;
    for (int i = tid; i < MROWS * SEQ; i += 512) ((ushort*)tokL)[i] = (ushort)xp[i];
  }
  // zero both hbuf parities (8192 B = 512 x 16 B)
  {
    uint4 z; z.x = z.y = z.z = z.w = 0u;
    ((uint4*)hbuf)[tid] = z;
  }

  // B fragments: Bf[g][ck] = W_hh[g*128 + u][ck*32 + lg*8 .. +7]  (f16)
  f16x8 Bf[4][4];
#pragma unroll
  for (int g = 0; g < 4; g++) {
    const float* wr = w_hh + (size_t)(g * 128 + u) * HID + lg * 8;
#pragma unroll
    for (int ck = 0; ck < 4; ck++) {
      const float4* p4 = (const float4*)(wr + ck * 32);
      float4 wa = p4[0], wb = p4[1];
      f16x8 f;
      f[0] = (_Float16)wa.x; f[1] = (_Float16)wa.y;
      f[2] = (_Float16)wa.z; f[3] = (_Float16)wa.w;
      f[4] = (_Float16)wb.x; f[5] = (_Float16)wb.y;
      f[6] = (_Float16)wb.z; f[7] = (_Float16)wb.w;
      Bf[g][ck] = f;
    }
  }

  // A-read offsets: row=l15, logical granule (ck*4+lg), physical = logical^row
  int aoff[4];
#pragma unroll
  for (int ck = 0; ck < 4; ck++)
    aoff[ck] = l15 * 256 + ((((ck * 4 + lg) ^ l15)) << 4);

  // h-write offsets (lg==0 lanes write BOTH rows of col u):
  // row r byte = r*256 + (((u>>3)^r)<<4) + (u&7)*2
  const int hwoff0 = u * 2;                                   // r=0 (swizzle id)
  const int hwoff1 = 256 + ((((u >> 3) ^ 1)) << 4) + (u & 7) * 2;  // r=1
  float cst0 = 0.0f, cst1 = 0.0f;

  __syncthreads();  // tokens + zeroed hbuf visible

  // xg prefetch, 2 deep, both rows, on lg==0 lanes only
  uint2 xgA0 = {0,0}, xgA1 = {0,0}, xgB0 = {0,0}, xgB1 = {0,0};
  if (lg == 0) {
    xgA0 = *(const uint2*)(P + (size_t)tokL[0][0] * G4 + u * 4);
    xgA1 = *(const uint2*)(P + (size_t)tokL[1][0] * G4 + u * 4);
    xgB0 = *(const uint2*)(P + (size_t)tokL[0][1] * G4 + u * 4);
    xgB1 = *(const uint2*)(P + (size_t)tokL[1][1] * G4 + u * 4);
  }

  const f32x4 fz = {0.f, 0.f, 0.f, 0.f};
  const char* hB = (const char*)hbuf;
  char* hW = (char*)hbuf;

#define MF(Areg, ckk, a0, a1, a2, a3) do {                                     \
    a0 = __builtin_amdgcn_mfma_f32_16x16x32_f16(Areg, Bf[0][ckk], a0, 0, 0, 0);\
    a1 = __builtin_amdgcn_mfma_f32_16x16x32_f16(Areg, Bf[1][ckk], a1, 0, 0, 0);\
    a2 = __builtin_amdgcn_mfma_f32_16x16x32_f16(Areg, Bf[2][ckk], a2, 0, 0, 0);\
    a3 = __builtin_amdgcn_mfma_f32_16x16x32_f16(Areg, Bf[3][ckk], a3, 0, 0, 0);\
  } while (0)

#define STEP(t, par) do {                                                      \
    const char* hc = hB + (par) * 4096;                                        \
    f16x8 A0 = *(const f16x8*)(hc + aoff[0]);                                  \
    f16x8 A1 = *(const f16x8*)(hc + aoff[1]);                                  \
    f16x8 A2 = *(const f16x8*)(hc + aoff[2]);                                  \
    f16x8 A3 = *(const f16x8*)(hc + aoff[3]);                                  \
    f32x4 a0 = fz, a1 = fz, a2 = fz, a3 = fz;                                  \
    MF(A0, 0, a0, a1, a2, a3);                                                 \
    MF(A1, 1, a0, a1, a2, a3);                                                 \
    MF(A2, 2, a0, a1, a2, a3);                                                 \
    MF(A3, 3, a0, a1, a2, a3);                                                 \
    if (lg == 0) {                                                             \
      uint2 xc0 = (par) ? xgB0 : xgA0;  /* capture BEFORE overwrite */         \
      uint2 xc1 = (par) ? xgB1 : xgA1;                                         \
      int tc = (t) + 2; if (tc > SEQ - 1) tc = SEQ - 1;                        \
      int tk0 = tokL[0][tc], tk1 = tokL[1][tc];                                \
      uint2 v0 = *(const uint2*)(P + (size_t)tk0 * G4 + u * 4);                \
      uint2 v1 = *(const uint2*)(P + (size_t)tk1 * G4 + u * 4);                \
      if (par) { xgB0 = v0; xgB1 = v1; } else { xgA0 = v0; xgA1 = v1; }        \
      char* hn = hW + ((par) ^ 1) * 4096;                                      \
      /* batch row 0: regs [0] */                                              \
      {                                                                        \
        half2t x0 = __builtin_bit_cast(half2t, xc0.x);                         \
        half2t x1 = __builtin_bit_cast(half2t, xc0.y);                         \
        float gi = a0[0] + (float)x0.x;                                        \
        float gf = a1[0] + (float)x0.y;                                        \
        float gc = a2[0] + (float)x1.x;                                        \
        float go = a3[0] + (float)x1.y;                                        \
        float fi = sigm(gi), ff = sigm(gf), gt = tanhfast(gc), fo = sigm(go);  \
        cst0 = ff * cst0 + fi * gt;                                            \
        float hh = fo * tanhfast(cst0);                                        \
        *(_Float16*)(hn + hwoff0) = (_Float16)hh;                              \
        if ((t) == SEQ - 1)                                                    \
          hout[((size_t)blk * MROWS + 0) * HID + u] = hh;                      \
      }                                                                        \
      /* batch row 1: regs [1] */                                              \
      {                                                                        \
        half2t x0 = __builtin_bit_cast(half2t, xc1.x);                         \
        half2t x1 = __builtin_bit_cast(half2t, xc1.y);                         \
        float gi = a0[1] + (float)x0.x;                                        \
        float gf = a1[1] + (float)x0.y;                                        \
        float gc = a2[1] + (float)x1.x;                                        \
        float go = a3[1] + (float)x1.y;                                        \
        float fi = sigm(gi), ff = sigm(gf), gt = tanhfast(gc), fo = sigm(go);  \
        cst1 = ff * cst1 + fi * gt;                                            \
        float hh = fo * tanhfast(cst1);                                        \
        *(_Float16*)(hn + hwoff1) = (_Float16)hh;                              \
        if ((t) == SEQ - 1)                                                    \
          hout[((size_t)blk * MROWS + 1) * HID + u] = hh;                      \
      }                                                                        \
    }                                                                          \
    barrier_lds_only();                                                        \
  } while (0)

  for (int t = 0; t < SEQ; t += 2) { STEP(t, 0); STEP(t + 1, 1); }
#undef STEP
#undef MF
}

// ---------------------------------------------------------------------------
// Fallback scan (no workspace for P): one row per block, fma path.
// ---------------------------------------------------------------------------
typedef _Float16 h2 __attribute__((ext_vector_type(2)));
DI float fdot2f(h2 a, h2 b, float c) { return c + (float)a.x * (float)b.x + (float)a.y * (float)b.y; }

__global__ __launch_bounds__(512, 4) void lstm_scan_fb(
    const int* __restrict__ x, const float* __restrict__ emb,
    const float* __restrict__ w_ih, const float* __restrict__ w_hh,
    const float* __restrict__ b_ih, const float* __restrict__ b_hh,
    float* __restrict__ hout)
{
  __shared__ int tokL[SEQ];
  __shared__ __align__(16) _Float16 h16[HID];
  __shared__ float g2h[2][G4];
  __shared__ __align__(8) h2 e16[2][NEMB / 2];

  const int tid = threadIdx.x;
  const int b = blockIdx.x;
  const int col = tid & 255;
  const int kh = tid >> 8;
  const int koff = kh * (HID / 2);

  {
    const int* xp = x + (size_t)b * SEQ;
#pragma unroll
    for (int i = 0; i < SEQ / 512; i++) tokL[tid + 512 * i] = xp[tid + 512 * i];
  }

  h2 w0[HID / 4], w1[HID / 4];
  {
    const float4* wr0 = (const float4*)(w_hh + (size_t)col * HID + koff);
    const float4* wr1 = (const float4*)(w_hh + (size_t)(col + 256) * HID + koff);
#pragma unroll
    for (int k = 0; k < HID / 8; k++) {
      float4 a = wr0[k];
      h2 p; p.x = (_Float16)a.x; p.y = (_Float16)a.y; w0[2 * k] = p;
      p.x = (_Float16)a.z; p.y = (_Float16)a.w; w0[2 * k + 1] = p;
      float4 bv = wr1[k];
      p.x = (_Float16)bv.x; p.y = (_Float16)bv.y; w1[2 * k] = p;
      p.x = (_Float16)bv.z; p.y = (_Float16)bv.w; w1[2 * k + 1] = p;
    }
  }
  h2 wih0[NEMB / 2], wih1[NEMB / 2];
  float bias0 = 0.0f, bias1 = 0.0f;
  if (kh == 0) {
    const float* wr0 = w_ih + (size_t)col * NEMB;
    const float* wr1 = w_ih + (size_t)(col + 256) * NEMB;
#pragma unroll
    for (int k = 0; k < NEMB / 2; k++) {
      h2 p;
      p.x = (_Float16)wr0[2 * k]; p.y = (_Float16)wr0[2 * k + 1]; wih0[k] = p;
      p.x = (_Float16)wr1[2 * k]; p.y = (_Float16)wr1[2 * k + 1]; wih1[k] = p;
    }
    bias0 = b_ih[col] + b_hh[col];
    bias1 = b_ih[col + 256] + b_hh[col + 256];
  }
  if (tid < HID) h16[tid] = (_Float16)0.0f;
  __syncthreads();

  float c = 0.0f;
  float2 einfl = {0.0f, 0.0f};
  if (tid < NEMB / 2) {
    float2 e0 = ((const float2*)(emb + (size_t)tokL[0] * NEMB))[tid];
    einfl    = ((const float2*)(emb + (size_t)tokL[1] * NEMB))[tid];
    h2 p; p.x = (_Float16)e0.x; p.y = (_Float16)e0.y;
    e16[0][tid] = p;
  }
  __syncthreads();

#define STEPF(t, par) do {                                                     \
    float xg0, xg1;                                                            \
    if (tid < NEMB / 2) {                                                      \
      int tc = (t) + 2; if (tc > SEQ - 1) tc = SEQ - 1;                        \
      h2 p; p.x = (_Float16)einfl.x; p.y = (_Float16)einfl.y;                  \
      e16[((t) + 1) & 1][tid] = p;                                             \
      einfl = ((const float2*)(emb + (size_t)tokL[tc] * NEMB))[tid];           \
    }                                                                          \
    if (kh == 0) {                                                             \
      xg0 = bias0; xg1 = bias1;                                                \
      _Pragma("unroll")                                                        \
      for (int k = 0; k < NEMB / 2; k++) {                                     \
        xg0 = fdot2f(wih0[k], e16[(par)][k], xg0);                             \
        xg1 = fdot2f(wih1[k], e16[(par)][k], xg1);                             \
      }                                                                        \
    } else { xg0 = 0.0f; xg1 = 0.0f; }                                         \
    const uint4* hv = (const uint4*)h16 + (kh << 3);                           \
    float s0 = xg0, u0 = 0.0f, s1 = xg1, u1 = 0.0f;                            \
    _Pragma("unroll")                                                          \
    for (int kt = 0; kt < HID / 16; kt++) {                                    \
      uint4 hq = hv[kt];                                                       \
      h2 ha = __builtin_bit_cast(h2, hq.x);                                    \
      h2 hb = __builtin_bit_cast(h2, hq.y);                                    \
      h2 hc = __builtin_bit_cast(h2, hq.z);                                    \
      h2 hd = __builtin_bit_cast(h2, hq.w);                                    \
      s0 = fdot2f(w0[4 * kt + 0], ha, s0);                                     \
      u0 = fdot2f(w0[4 * kt + 1], hb, u0);                                     \
      s0 = fdot2f(w0[4 * kt + 2], hc, s0);                                     \
      u0 = fdot2f(w0[4 * kt + 3], hd, u0);                                     \
      s1 = fdot2f(w1[4 * kt + 0], ha, s1);                                     \
      u1 = fdot2f(w1[4 * kt + 1], hb, u1);                                     \
      s1 = fdot2f(w1[4 * kt + 2], hc, s1);                                     \
      u1 = fdot2f(w1[4 * kt + 3], hd, u1);                                     \
    }                                                                          \
    g2h[kh][col] = s0 + u0;                                                    \
    g2h[kh][col + 256] = s1 + u1;                                              \
    barrier_lds_only();                                                        \
    if (tid < HID) {                                                           \
      float gi = g2h[0][tid]           + g2h[1][tid];                          \
      float gf = g2h[0][HID + tid]     + g2h[1][HID + tid];                    \
      float gc = g2h[0][2 * HID + tid] + g2h[1][2 * HID + tid];                \
      float go = g2h[0][3 * HID + tid] + g2h[1][3 * HID + tid];                \
      float fi = sigm(gi), ff = sigm(gf), gt = tanhfast(gc), fo = sigm(go);    \
      c = ff * c + fi * gt;                                                    \
      float hh = fo * tanhfast(c);                                             \
      h16[tid] = (_Float16)hh;                                                 \
      if ((t) == SEQ - 1) hout[(size_t)b * HID + tid] = hh;                    \
    }                                                                          \
    barrier_lds_only();                                                        \
  } while (0)

  for (int t = 0; t < SEQ; t += 2) { STEPF(t, 0); STEPF(t + 1, 1); }
#undef STEPF
}

// ---------------------------------------------------------------------------
// Phase C: FC  out[512,2000] = h[512,128] @ w_fc^T + b_fc.
// ---------------------------------------------------------------------------
#define FCR 64
#define FCC 64
__global__ __launch_bounds__(256) void fc_kernel(
    const float* __restrict__ h, const float* __restrict__ w_fc,
    const float* __restrict__ b_fc, float* __restrict__ out)
{
  __shared__ float aT[HID][FCR];
  __shared__ float bT[HID][FCC];
  const int tid = threadIdx.x;
  const int r0 = blockIdx.y * FCR;
  const int c0 = blockIdx.x * FCC;

  for (int f = tid; f < FCR * (HID / 4); f += 256) {
    int row = f >> 5, q = f & 31;
    float4 v = ((const float4*)h)[(((size_t)(r0 + row)) << 5) + q];
    aT[4 * q + 0][row] = v.x; aT[4 * q + 1][row] = v.y;
    aT[4 * q + 2][row] = v.z; aT[4 * q + 3][row] = v.w;
    int wrow = c0 + row;
    float4 wv;
    if (wrow < NCLS) wv = ((const float4*)w_fc)[(((size_t)wrow) << 5) + q];
    else { wv.x = 0.f; wv.y = 0.f; wv.z = 0.f; wv.w = 0.f; }
    bT[4 * q + 0][row] = wv.x; bT[4 * q + 1][row] = wv.y;
    bT[4 * q + 2][row] = wv.z; bT[4 * q + 3][row] = wv.w;
  }
  __syncthreads();

  const int cr = tid & 15, rr = tid >> 4;
  float acc[4][4];
#pragma unroll
  for (int i = 0; i < 4; i++)
#pragma unroll
    for (int j = 0; j < 4; j++) acc[i][j] = 0.0f;

#pragma unroll 4
  for (int k = 0; k < HID; k++) {
    float4 av = *(const float4*)&aT[k][4 * rr];
    float4 bv = *(const float4*)&bT[k][4 * cr];
    float a[4] = {av.x, av.y, av.z, av.w};
    float bb[4] = {bv.x, bv.y, bv.z, bv.w};
#pragma unroll
    for (int i = 0; i < 4; i++)
#pragma unroll
      for (int j = 0; j < 4; j++) acc[i][j] += a[i] * bb[j];
  }

#pragma unroll
  for (int j = 0; j < 4; j++) {
    int cc = c0 + 4 * cr + j;
    if (cc < NCLS) {
      float bias = b_fc[cc];
#pragma unroll
      for (int i = 0; i < 4; i++)
        out[(size_t)(r0 + 4 * rr + i) * NCLS + cc] = acc[i][j] + bias;
    }
  }
}

extern "C" void kernel_launch(void* const* d_in, const int* in_sizes, int n_in,
                              void* d_out, int out_size, void* d_ws, size_t ws_size,
                              hipStream_t stream) {
  const int*   xx   = (const int*)d_in[0];
  const float* emb  = (const float*)d_in[1];
  const float* w_ih = (const float*)d_in[2];
  const float* w_hh = (const float*)d_in[3];
  const float* b_ih = (const float*)d_in[4];
  const float* b_hh = (const float*)d_in[5];
  const float* w_fc = (const float*)d_in[6];
  const float* b_fc = (const float*)d_in[7];
  float* out = (float*)d_out;

  const size_t pbytes = (size_t)VOCAB * G4 * sizeof(_Float16); // 51.5 MB
  const size_t palign = (pbytes + 255) & ~(size_t)255;
  const size_t hbytes = (size_t)BATCH * HID * sizeof(float);

  float* hout;
  if (ws_size >= palign + hbytes) {
    _Float16* P = (_Float16*)d_ws;
    hout = (float*)((char*)d_ws + palign);
    build_P<<<(VOCAB + VROWS - 1) / VROWS, 512, 0, stream>>>(emb, w_ih, b_ih, b_hh, P);
    lstm_mfma4<<<NBLK2, 512, 0, stream>>>(xx, w_hh, P, hout);
  } else {
    hout = (float*)d_ws;
    lstm_scan_fb<<<BATCH, 512, 0, stream>>>(xx, emb, w_ih, w_hh, b_ih, b_hh, hout);
  }
  dim3 fcg((NCLS + FCC - 1) / FCC, BATCH / FCR);
  fc_kernel<<<fcg, 256, 0, stream>>>(hout, w_fc, b_fc, out);
}